// Round 15
// baseline (18681.281 us; speedup 1.0000x reference)
//
#include <hip/hip_runtime.h>
#include <stdint.h>

#define T_LEN 512
#define H_DIM 512
#define B_TOT 4096
#define GATE_D 514
#define CLUSTERS 16
#define RANKS 16        // blocks per cluster
#define CROWS 256       // batch rows per cluster
#define OWNC 32         // h-columns owned per block
#define NTHR 512        // 8 waves: 0-3 G1 (z,r), 4-7 G2 (h~, state)
#define BARPAD 256      // uints per cluster barrier slot (1KB)
#define ZS 33           // z_s row stride (f32, padded)

typedef short s16x8 __attribute__((ext_vector_type(8)));
typedef float f32x4 __attribute__((ext_vector_type(4)));

__device__ __forceinline__ ushort f2bf(float f) {
    uint32_t u = __builtin_bit_cast(uint32_t, f);
    u += 0x7FFF + ((u >> 16) & 1);     // RNE
    return (ushort)(u >> 16);
}
__device__ __forceinline__ float bf2f(ushort h) {
    uint32_t u = ((uint32_t)h) << 16;
    return __builtin_bit_cast(float, u);
}
__device__ __forceinline__ float sigmoid_f(float x) {
    return 1.0f / (1.0f + __expf(-x));
}
__device__ __forceinline__ float tanh_f(float x) {
    float ax = fabsf(x);
    float e  = __expf(2.0f * ax);
    float t  = 1.0f - 2.0f / (e + 1.0f);
    return copysignf(t, x);
}
__device__ __forceinline__ void vm0() {
    asm volatile("s_waitcnt vmcnt(0)" ::: "memory");
}

// ---------------- K0: masked mean over time ----------------
__global__ void k_xmean(const float* __restrict__ x, const float* __restrict__ m,
                        float* __restrict__ xmean) {
    int b = blockIdx.x;
    int l = threadIdx.x;
    const float* xr = x + (size_t)b * T_LEN;
    const float* mr = m + (size_t)b * T_LEN;
    float sx = 0.f, sm = 0.f;
    #pragma unroll
    for (int i = 0; i < T_LEN / 64; ++i) {
        float mv = mr[l + i * 64];
        sx += xr[l + i * 64] * mv;
        sm += mv;
    }
    for (int off = 32; off; off >>= 1) {
        sx += __shfl_down(sx, off);
        sm += __shfl_down(sm, off);
    }
    if (l == 0) xmean[b] = sx / sm;
}

// ---------------- K_init: zero cluster barrier slots ----------------
__global__ void k_init(unsigned int* barc) {
    int i = threadIdx.x + blockIdx.x * blockDim.x;
    if (i < CLUSTERS * BARPAD) barc[i] = 0u;
}

// ---------------- fenced block-wide cluster barrier (proven; pre/post loop) ----------------
__device__ __forceinline__ void bar_slow(unsigned int* cnt, unsigned int target) {
    vm0();
    __syncthreads();
    if (threadIdx.x == 0) {
        __builtin_amdgcn_fence(__ATOMIC_RELEASE, "agent");
        __hip_atomic_fetch_add(cnt, 1u, __ATOMIC_RELAXED, __HIP_MEMORY_SCOPE_AGENT);
        while (__hip_atomic_load(cnt, __ATOMIC_RELAXED, __HIP_MEMORY_SCOPE_AGENT) < target)
            __builtin_amdgcn_s_sleep(1);
        __builtin_amdgcn_fence(__ATOMIC_ACQUIRE, "agent");
    }
    __syncthreads();
}

// ---------------- per-wave-index cluster events (round-11 proven) ----------------
// arrive drains vm AND lgkm: global exchange stores AND block-local LDS handoffs
// (z_s, stage, xi_s) must be complete/visible before the counter bump.
__device__ __forceinline__ void wave_arrive(unsigned int* cw, bool fastc) {
    asm volatile("s_waitcnt vmcnt(0) lgkmcnt(0)" ::: "memory");
    if ((threadIdx.x & 63) == 0) {
        if (!fastc) __builtin_amdgcn_fence(__ATOMIC_RELEASE, "agent");
        __hip_atomic_fetch_add(cw, 1u, __ATOMIC_RELAXED, __HIP_MEMORY_SCOPE_AGENT);
    }
}
__device__ __forceinline__ void wave_wait(unsigned int* cw, unsigned int target, bool fastc) {
    while (__hip_atomic_load(cw, __ATOMIC_RELAXED, __HIP_MEMORY_SCOPE_AGENT) < target)
        __builtin_amdgcn_s_sleep(1);
    if (fastc) { asm volatile("buffer_inv" ::: "memory"); vm0(); }
    else __builtin_amdgcn_fence(__ATOMIC_ACQUIRE, "agent");
}

// ---------------- main persistent kernel ----------------
// 256 blocks x 512 threads, 1 block/CU. Cluster = 16 blocks / 256 rows (same-XCD
// heuristic, runtime-verified; fenced fallback). PRODUCER/CONSUMER SPLIT:
// waves 0-3 (G1-j): GEMM1 z,r for rows [64j,64j+64) (4 frags) -> z to z_s LDS,
//   r*hd (hd bf16 from stage) -> stage -> rhc. waves 4-7 (G2-j): GEMM2 h~ for the
//   same rows, h-state in regs, fused gamma(t+1) -> stage -> hdc. Each B-frag read
//   now feeds 4 MFMA (vs 2) -> block LDS B-reads 768->384 per step.
// Events per j: cnt_hd (G2 arrives, G1 waits), cnt_rh (G1 arrives, G2 waits).
__global__ __launch_bounds__(NTHR) void k_grud(
    const float* __restrict__ x,   const float* __restrict__ xl,
    const float* __restrict__ itv, const float* __restrict__ msk,
    const float* __restrict__ Wgx, const float* __restrict__ bgx,
    const float* __restrict__ Wgh, const float* __restrict__ bgh,
    const float* __restrict__ Wz,  const float* __restrict__ bz,
    const float* __restrict__ Wr,  const float* __restrict__ br,
    const float* __restrict__ Wh,  const float* __restrict__ bh,
    const float* __restrict__ Wo,  const float* __restrict__ bo,
    const float* __restrict__ xmean,
    ushort* __restrict__ hdx, ushort* __restrict__ rhx,
    float* __restrict__ osum, unsigned int* __restrict__ barc,
    float* __restrict__ out)
{
    __shared__ ushort wfrag[96 * 512];        // 98304 B  B-frags: z 0-31, r 32-63, h 64-95
    __shared__ ushort stage[16 * 512];        // 16384 B  frag image (hd from G2 / rh from G1)
    __shared__ float  z_s[CROWS * ZS];        // 33792 B  z handoff G1->G2 (fp32)
    __shared__ float  xi_s[CROWS], mts_s[CROWS], itn_s[CROWS];  // 3072 B
    __shared__ float4 epi_s[96];              // 1536 B   {bias, W[:,0], W[:,513]} per gate/own col
    __shared__ float2 ghb_s[OWNC];            // 256 B    {Wgh, bgh} own cols
    __shared__ unsigned int flag_s;

    const int tid = threadIdx.x;
    const int b   = blockIdx.x;
    const int cluster = (b & 7) * 2 + ((b >> 3) >> 4);   // same-XCD grouping heuristic
    const int rank    = (b >> 3) & 15;
    const int wv = tid >> 6, l = tid & 63;
    const bool isG1 = (wv < 4);
    const int j = wv & 3;
    const int colb = l & 15, qg = l >> 4;
    const int r0 = cluster * CROWS;

    unsigned int* base    = barc + cluster * BARPAD;   // [0] slow cnt, [4..19] xcd
    unsigned int* xcd_arr = base + 4;
    unsigned int* cnt_hd  = base + 64  + j * 16;       // hd(t) ready events (per j)
    unsigned int* cnt_rh  = base + 128 + j * 16;       // rh(t) ready events (per j)
    ushort* hdc = hdx + (size_t)cluster * CROWS * H_DIM;
    ushort* rhc = rhx + (size_t)cluster * CROWS * H_DIM;
    const s16x8* WF = (const s16x8*)wfrag;
    const s16x8* HD = (const s16x8*)hdc;
    const s16x8* RH = (const s16x8*)rhc;

    // ---- one-time init: weight fragments (LDS), zero stage ----
    for (int s = tid; s < 96 * 64; s += NTHR) {
        int fi = s >> 6, ln = s & 63;
        int g = fi >> 5, nt = (fi >> 4) & 1, kt = fi & 15;
        const float* W = (g == 0) ? Wz : (g == 1) ? Wr : Wh;
        int colg = rank * OWNC + nt * 16 + (ln & 15);
        int c0 = 1 + kt * 32 + (ln >> 4) * 8;
        ushort tb[8];
        #pragma unroll
        for (int jj = 0; jj < 8; ++jj) tb[jj] = f2bf(W[(size_t)colg * GATE_D + c0 + jj]);
        *(s16x8*)&wfrag[s * 8] = *(s16x8*)tb;
    }
    for (int i = tid; i < 4096; i += NTHR) ((uint32_t*)stage)[i] = 0u;   // hd(0)=0 image
    for (int i = tid; i < 96; i += NTHR) {
        int g = i >> 5, c = i & 31;
        const float* W  = (g == 0) ? Wz : (g == 1) ? Wr : Wh;
        const float* bb = (g == 0) ? bz : (g == 1) ? br : bh;
        int colg = rank * OWNC + c;
        epi_s[i] = make_float4(bb[colg], W[(size_t)colg * GATE_D],
                               W[(size_t)colg * GATE_D + GATE_D - 1], 0.f);
    }
    if (tid < OWNC) ghb_s[tid] = make_float2(Wgh[rank * OWNC + tid], bgh[rank * OWNC + tid]);
    const float wgx = Wgx[0], bgx0 = bgx[0];
    const float xmv = xmean[r0 + j * 64 + l];            // row j*64+l (used by G1)

    // ---- zero hdc (hd(0)=0), all 8 waves cover 16 frags ----
    #pragma unroll
    for (int i = 0; i < 2; ++i) {
        int s = tid + i * NTHR;
        *(s16x8*)((char*)hdc + ((size_t)(s >> 6) * 1024 + (size_t)rank * 64 + (s & 63)) * 16) =
            (s16x8){0,0,0,0,0,0,0,0};
    }

    // ---- registration: publish XCC_ID, fenced barrier, verify cluster uniformity ----
    if (tid == 0) {
        unsigned int myxcc;
        asm volatile("s_getreg_b32 %0, hwreg(HW_REG_XCC_ID)" : "=s"(myxcc));
        xcd_arr[rank] = myxcc;
    }
    bar_slow(base, RANKS);                     // slow-counter use #1 (flushes hdc zeros)
    if (tid == 0) {
        unsigned int x0 = xcd_arr[0], same = 1;
        #pragma unroll
        for (int rk = 1; rk < RANKS; ++rk) same &= (xcd_arr[rk] == x0) ? 1u : 0u;
        flag_s = same;
    }
    __syncthreads();
    const bool fastc = (flag_s != 0);

    if (!isG1) wave_arrive(cnt_hd, fastc);     // hd(0) ready: count -> 16 per j

    if (isG1) {
        // ================= G1 role: z,r producer =================
        for (int t = 0; t < T_LEN; ++t) {
            // issue input loads (overlap event poll), write xi_s after wait
            size_t idx = (size_t)(r0 + j * 64 + l) * T_LEN + t;
            float xv = x[idx], xlv = xl[idx], iv = itv[idx], mv = msk[idx];
            wave_wait(cnt_hd, (unsigned int)(16 * (t + 1)), fastc);
            float gx = __expf(-fmaxf(iv * wgx + bgx0, 0.f));
            xi_s[j * 64 + l]  = mv * xv + (1.f - mv) * (gx * xlv + (1.f - gx) * xmv);
            mts_s[j * 64 + l] = mv;

            // GEMM1: 4 frags x 2 nt x {z,r}; each B-read feeds 4 MFMA
            f32x4 accz[4][2], accr[4][2];
            #pragma unroll
            for (int i = 0; i < 4; ++i)
                #pragma unroll
                for (int nt = 0; nt < 2; ++nt) { accz[i][nt] = (f32x4){0,0,0,0}; accr[i][nt] = (f32x4){0,0,0,0}; }
            #pragma unroll
            for (int kt = 0; kt < 16; ++kt) {
                s16x8 a[4];
                #pragma unroll
                for (int i = 0; i < 4; ++i)
                    a[i] = HD[(((4 * j + i) * 16 + kt)) * 64 + l];
                #pragma unroll
                for (int nt = 0; nt < 2; ++nt) {
                    s16x8 bz_ = WF[(     nt * 16 + kt) * 64 + l];
                    s16x8 br_ = WF[(32 + nt * 16 + kt) * 64 + l];
                    #pragma unroll
                    for (int i = 0; i < 4; ++i) {
                        accz[i][nt] = __builtin_amdgcn_mfma_f32_16x16x32_bf16(a[i], bz_, accz[i][nt], 0, 0, 0);
                        accr[i][nt] = __builtin_amdgcn_mfma_f32_16x16x32_bf16(a[i], br_, accr[i][nt], 0, 0, 0);
                    }
                }
            }
            // epilogue: z -> z_s; rh = r * hd(bf16 from stage) -> stage (in place)
            #pragma unroll
            for (int i = 0; i < 4; ++i) {
                int mt = 4 * j + i;
                #pragma unroll
                for (int nt = 0; nt < 2; ++nt) {
                    int c = nt * 16 + colb;
                    float4 ez = epi_s[c];
                    float4 er = epi_s[32 + c];
                    int grp = (c >> 3) & 3, jj = c & 7;
                    #pragma unroll
                    for (int q = 0; q < 4; ++q) {
                        int row = mt * 16 + qg * 4 + q;
                        float xiv = xi_s[row], mtv = mts_s[row];
                        float zz = sigmoid_f(accz[i][nt][q] + ez.x + xiv * ez.y + mtv * ez.z);
                        z_s[row * ZS + c] = zz;
                        int sidx = ((mt * 64) + (qg * 4 + q) + grp * 16) * 8 + jj;
                        float hd = bf2f(stage[sidx]);
                        float rr = sigmoid_f(accr[i][nt][q] + er.x + xiv * er.y + mtv * er.z);
                        stage[sidx] = f2bf(rr * hd);
                    }
                }
            }
            // copy own 4 frags -> rhc
            #pragma unroll
            for (int i = 0; i < 4; ++i) {
                int f = 4 * j + i;
                *(s16x8*)((char*)rhc + (((size_t)f * 16 + rank) * 64 + l) * 16) =
                    *(const s16x8*)&stage[(f * 64 + l) * 8];
            }
            wave_arrive(cnt_rh, fastc);                   // rh(t) published
        }
    } else {
        // ================= G2 role: h~ consumer, state owner =================
        float hdq[4][2][4];
        #pragma unroll
        for (int i = 0; i < 4; ++i)
            #pragma unroll
            for (int nt = 0; nt < 2; ++nt)
                #pragma unroll
                for (int q = 0; q < 4; ++q) hdq[i][nt][q] = 0.f;

        for (int t = 0; t < T_LEN; ++t) {
            const bool last = (t + 1 == T_LEN);
            int tn = last ? t : t + 1;
            float iv_n = itv[(size_t)(r0 + j * 64 + l) * T_LEN + tn];  // overlap poll
            wave_wait(cnt_rh, (unsigned int)(16 * (t + 1)), fastc);
            itn_s[j * 64 + l] = iv_n;

            // GEMM2: 4 frags x 2 nt
            f32x4 acc2[4][2];
            #pragma unroll
            for (int i = 0; i < 4; ++i)
                #pragma unroll
                for (int nt = 0; nt < 2; ++nt) acc2[i][nt] = (f32x4){0,0,0,0};
            #pragma unroll
            for (int kt = 0; kt < 16; ++kt) {
                s16x8 a[4];
                #pragma unroll
                for (int i = 0; i < 4; ++i)
                    a[i] = RH[(((4 * j + i) * 16 + kt)) * 64 + l];
                #pragma unroll
                for (int nt = 0; nt < 2; ++nt) {
                    s16x8 bh_ = WF[(64 + nt * 16 + kt) * 64 + l];
                    #pragma unroll
                    for (int i = 0; i < 4; ++i)
                        acc2[i][nt] = __builtin_amdgcn_mfma_f32_16x16x32_bf16(a[i], bh_, acc2[i][nt], 0, 0, 0);
                }
            }
            // epilogue: h~ + state update (z from z_s) + fused gamma(t+1); hd -> stage
            #pragma unroll
            for (int i = 0; i < 4; ++i) {
                int mt = 4 * j + i;
                #pragma unroll
                for (int nt = 0; nt < 2; ++nt) {
                    int c = nt * 16 + colb;
                    float4 eh = epi_s[64 + c];
                    float2 gb = ghb_s[c];
                    int grp = (c >> 3) & 3, jj = c & 7;
                    #pragma unroll
                    for (int q = 0; q < 4; ++q) {
                        int row = mt * 16 + qg * 4 + q;
                        float ht = tanh_f(acc2[i][nt][q] + eh.x + xi_s[row] * eh.y + mts_s[row] * eh.z);
                        float hd = hdq[i][nt][q];
                        float zz = z_s[row * ZS + c];
                        float hn = hd + zz * (ht - hd);
                        float g  = last ? 1.f : __expf(-fmaxf(itn_s[row] * gb.x + gb.y, 0.f));
                        float hdn = hn * g;
                        hdq[i][nt][q] = hdn;
                        if (!last)
                            stage[((mt * 64) + (qg * 4 + q) + grp * 16) * 8 + jj] = f2bf(hdn);
                    }
                }
            }
            if (!last) {
                #pragma unroll
                for (int i = 0; i < 4; ++i) {
                    int f = 4 * j + i;
                    *(s16x8*)((char*)hdc + (((size_t)f * 16 + rank) * 64 + l) * 16) =
                        *(const s16x8*)&stage[(f * 64 + l) * 8];
                }
            }
            wave_arrive(cnt_hd, fastc);                   // hd(t+1) published
        }

        // ---- output head (G2 owns state): partials over own cols, shfl reduce ----
        {
            float wo0 = Wo[rank * OWNC + colb];
            float wo1 = Wo[rank * OWNC + 16 + colb];
            #pragma unroll
            for (int i = 0; i < 4; ++i) {
                #pragma unroll
                for (int q = 0; q < 4; ++q) {
                    int row = (4 * j + i) * 16 + qg * 4 + q;
                    float p = hdq[i][0][q] * wo0 + hdq[i][1][q] * wo1;
                    #pragma unroll
                    for (int off = 1; off < 16; off <<= 1) p += __shfl_xor(p, off);
                    if (colb == 0) osum[(size_t)(r0 + row) * RANKS + rank] = p;
                }
            }
        }
    }

    bar_slow(base, 2 * RANKS);                 // slow-counter use #2 (fenced, any placement)
    if (rank == 0 && tid < CROWS) {
        float s = 0.f;
        #pragma unroll
        for (int rk = 0; rk < RANKS; ++rk) s += osum[(size_t)(r0 + tid) * RANKS + rk];
        out[r0 + tid] = sigmoid_f(s + bo[0]);
    }
}

extern "C" void kernel_launch(void* const* d_in, const int* in_sizes, int n_in,
                              void* d_out, int out_size, void* d_ws, size_t ws_size,
                              hipStream_t stream) {
    const float* x    = (const float*)d_in[0];
    const float* xl   = (const float*)d_in[1];
    const float* itv  = (const float*)d_in[2];
    const float* msk  = (const float*)d_in[3];
    const float* Wgx  = (const float*)d_in[4];
    const float* bgx  = (const float*)d_in[5];
    const float* Wgh  = (const float*)d_in[6];
    const float* bgh  = (const float*)d_in[7];
    const float* Wz   = (const float*)d_in[8];
    const float* bz   = (const float*)d_in[9];
    const float* Wr   = (const float*)d_in[10];
    const float* br   = (const float*)d_in[11];
    const float* Wh   = (const float*)d_in[12];
    const float* bh   = (const float*)d_in[13];
    const float* Wo   = (const float*)d_in[14];
    const float* bo   = (const float*)d_in[15];

    char* ws = (char*)d_ws;
    float*        xmean = (float*)ws;                               // 16384 B
    unsigned int* barc  = (unsigned int*)(ws + 16384);              // 16384 B
    float*        osum  = (float*)(ws + 32768);                     // 262144 B
    ushort*       hdx   = (ushort*)(ws + 294912);                   // 4 MB
    ushort*       rhx   = (ushort*)(ws + 294912 + 4194304);         // 4 MB

    k_init<<<16, 256, 0, stream>>>(barc);
    k_xmean<<<B_TOT, 64, 0, stream>>>(x, msk, xmean);
    k_grud<<<CLUSTERS * RANKS, NTHR, 0, stream>>>(
        x, xl, itv, msk, Wgx, bgx, Wgh, bgh,
        Wz, bz, Wr, br, Wh, bh, Wo, bo,
        xmean, hdx, rhx, osum, barc, (float*)d_out);
}

// Round 16
// 7112.820 us; speedup vs baseline: 2.6264x; 2.6264x over previous
//
#include <hip/hip_runtime.h>
#include <hip/hip_bf16.h>
#include <stdint.h>

#define T_LEN 512
#define H_DIM 512
#define B_TOT 4096
#define GATE_D 514
#define CLUSTERS 16
#define RANKS 16        // blocks per cluster
#define CROWS 256       // batch rows per cluster
#define OWNC 32         // h-columns owned per block
#define NTHR 512        // 8 waves
#define BARPAD 256      // uints per cluster barrier slot (1KB)

typedef short s16x8 __attribute__((ext_vector_type(8)));
typedef float f32x4 __attribute__((ext_vector_type(4)));

// Native RNE f32->bf16 (compiler-recognizable; fuses pairs into v_cvt_pk_bf16_f32).
__device__ __forceinline__ ushort f2bf(float f) {
    return __bfloat16_as_ushort(__float2bfloat16(f));
}
// sigmoid/tanh with v_rcp_f32 (1-ulp) instead of the precise-div sequence (~10 insts).
__device__ __forceinline__ float sigmoid_f(float x) {
    return __builtin_amdgcn_rcpf(1.0f + __expf(-x));
}
__device__ __forceinline__ float tanh_f(float x) {
    float ax = fabsf(x);
    float e  = __expf(2.0f * ax);              // inf ok: rcp(inf)=0 -> t=1
    float t  = 1.0f - 2.0f * __builtin_amdgcn_rcpf(e + 1.0f);
    return copysignf(t, x);
}
__device__ __forceinline__ void vm0() {
    asm volatile("s_waitcnt vmcnt(0)" ::: "memory");
}

// ---------------- K0: masked mean over time ----------------
__global__ void k_xmean(const float* __restrict__ x, const float* __restrict__ m,
                        float* __restrict__ xmean) {
    int b = blockIdx.x;
    int l = threadIdx.x;
    const float* xr = x + (size_t)b * T_LEN;
    const float* mr = m + (size_t)b * T_LEN;
    float sx = 0.f, sm = 0.f;
    #pragma unroll
    for (int i = 0; i < T_LEN / 64; ++i) {
        float mv = mr[l + i * 64];
        sx += xr[l + i * 64] * mv;
        sm += mv;
    }
    for (int off = 32; off; off >>= 1) {
        sx += __shfl_down(sx, off);
        sm += __shfl_down(sm, off);
    }
    if (l == 0) xmean[b] = sx / sm;
}

// ---------------- K_init: zero cluster barrier slots ----------------
__global__ void k_init(unsigned int* barc) {
    int i = threadIdx.x + blockIdx.x * blockDim.x;
    if (i < CLUSTERS * BARPAD) barc[i] = 0u;
}

// ---------------- fenced block-wide cluster barrier (proven; pre/post loop) ----------------
__device__ __forceinline__ void bar_slow(unsigned int* cnt, unsigned int target) {
    vm0();
    __syncthreads();
    if (threadIdx.x == 0) {
        __builtin_amdgcn_fence(__ATOMIC_RELEASE, "agent");
        __hip_atomic_fetch_add(cnt, 1u, __ATOMIC_RELAXED, __HIP_MEMORY_SCOPE_AGENT);
        while (__hip_atomic_load(cnt, __ATOMIC_RELAXED, __HIP_MEMORY_SCOPE_AGENT) < target)
            __builtin_amdgcn_s_sleep(1);
        __builtin_amdgcn_fence(__ATOMIC_ACQUIRE, "agent");
    }
    __syncthreads();
}

// ---------------- per-wave-index cluster events (round-11 proven) ----------------
__device__ __forceinline__ void wave_arrive(unsigned int* cw, bool fastc) {
    vm0();
    if ((threadIdx.x & 63) == 0) {
        if (!fastc) __builtin_amdgcn_fence(__ATOMIC_RELEASE, "agent");
        __hip_atomic_fetch_add(cw, 1u, __ATOMIC_RELAXED, __HIP_MEMORY_SCOPE_AGENT);
    }
}
__device__ __forceinline__ void wave_wait(unsigned int* cw, unsigned int target, bool fastc) {
    while (__hip_atomic_load(cw, __ATOMIC_RELAXED, __HIP_MEMORY_SCOPE_AGENT) < target)
        __builtin_amdgcn_s_sleep(1);
    if (fastc) { asm volatile("buffer_inv" ::: "memory"); vm0(); }
    else __builtin_amdgcn_fence(__ATOMIC_ACQUIRE, "agent");
}

// ---------------- main persistent kernel ----------------
// EXACT round-11 structure (6988us proven: per-wave-index event pipelines, h-state
// in 16 regs/thread, fused gamma(t+1), no block-wide sync in the loop; VGPR=128,
// no spill). This round's single variable: VALU diet — native bf16 casts +
// v_rcp_f32 sigmoid/tanh. No stagger (R13: -13%), no reg B-cache (R9/R12: spill),
// no role split (R15: -167%).
__global__ __launch_bounds__(NTHR) void k_grud(
    const float* __restrict__ x,   const float* __restrict__ xl,
    const float* __restrict__ itv, const float* __restrict__ msk,
    const float* __restrict__ Wgx, const float* __restrict__ bgx,
    const float* __restrict__ Wgh, const float* __restrict__ bgh,
    const float* __restrict__ Wz,  const float* __restrict__ bz,
    const float* __restrict__ Wr,  const float* __restrict__ br,
    const float* __restrict__ Wh,  const float* __restrict__ bh,
    const float* __restrict__ Wo,  const float* __restrict__ bo,
    const float* __restrict__ xmean,
    ushort* __restrict__ hdx, ushort* __restrict__ rhx,
    float* __restrict__ osum, unsigned int* __restrict__ barc,
    float* __restrict__ out)
{
    __shared__ ushort wfrag[96 * 512];        // 98304 B  B-frags: z 0-31, r 32-63, h 64-95
    __shared__ ushort stage[16 * 512];        // 16384 B  frag image; wave wv owns frags 2wv,2wv+1
    __shared__ float  xi_w[8][32], mts_w[8][32], itn_w[8][32];  // 3072 B wave-private scalars
    __shared__ float4 epi_s[96];              // 1536 B   {bias, W[:,0], W[:,513]} per gate/own col
    __shared__ float2 ghb_s[OWNC];            // 256 B    {Wgh, bgh} own cols
    __shared__ unsigned int flag_s;

    const int tid = threadIdx.x;
    const int b   = blockIdx.x;
    const int cluster = (b & 7) * 2 + ((b >> 3) >> 4);   // same-XCD grouping heuristic
    const int rank    = (b >> 3) & 15;
    const int wv = tid >> 6, l = tid & 63;
    const int colb = l & 15, qg = l >> 4;
    const int r0 = cluster * CROWS;

    unsigned int* base    = barc + cluster * BARPAD;   // [0] slow cnt, [4..19] xcd, [64+16w] wave cnt
    unsigned int* xcd_arr = base + 4;
    unsigned int* cw      = base + 64 + wv * 16;       // per-wave-index counter (64B apart)
    ushort* hdc = hdx + (size_t)cluster * CROWS * H_DIM;
    ushort* rhc = rhx + (size_t)cluster * CROWS * H_DIM;
    const s16x8* WF = (const s16x8*)wfrag;
    const s16x8* HD = (const s16x8*)hdc;
    const s16x8* RH = (const s16x8*)rhc;

    // ---- one-time init: weight fragments (LDS) ----
    for (int s = tid; s < 96 * 64; s += NTHR) {
        int fi = s >> 6, ln = s & 63;
        int g = fi >> 5, nt = (fi >> 4) & 1, kt = fi & 15;
        const float* W = (g == 0) ? Wz : (g == 1) ? Wr : Wh;
        int colg = rank * OWNC + nt * 16 + (ln & 15);
        int c0 = 1 + kt * 32 + (ln >> 4) * 8;
        ushort tb[8];
        #pragma unroll
        for (int j = 0; j < 8; ++j) tb[j] = f2bf(W[(size_t)colg * GATE_D + c0 + j]);
        *(s16x8*)&wfrag[s * 8] = *(s16x8*)tb;
    }
    for (int i = tid; i < 96; i += NTHR) {
        int g = i >> 5, c = i & 31;
        const float* W  = (g == 0) ? Wz : (g == 1) ? Wr : Wh;
        const float* bb = (g == 0) ? bz : (g == 1) ? br : bh;
        int colg = rank * OWNC + c;
        epi_s[i] = make_float4(bb[colg], W[(size_t)colg * GATE_D],
                               W[(size_t)colg * GATE_D + GATE_D - 1], 0.f);
    }
    if (tid < OWNC) ghb_s[tid] = make_float2(Wgh[rank * OWNC + tid], bgh[rank * OWNC + tid]);
    const float wgx = Wgx[0], bgx0 = bgx[0];
    const float xmv = (l < 32) ? xmean[r0 + wv * 32 + l] : 0.f;

    // ---- registration: publish XCC_ID, fenced barrier, verify cluster uniformity ----
    if (tid == 0) {
        unsigned int myxcc;
        asm volatile("s_getreg_b32 %0, hwreg(HW_REG_XCC_ID)" : "=s"(myxcc));
        xcd_arr[rank] = myxcc;
    }
    bar_slow(base, RANKS);                     // slow-counter use #1
    if (tid == 0) {
        unsigned int x0 = xcd_arr[0], same = 1;
        #pragma unroll
        for (int rk = 1; rk < RANKS; ++rk) same &= (xcd_arr[rk] == x0) ? 1u : 0u;
        flag_s = same;
    }
    __syncthreads();
    const bool fastc = (flag_s != 0);

    // ---- publish hd(0)=0 for own frags (wave-private) + event 1 ----
    #pragma unroll
    for (int i = 0; i < 2; ++i) {
        int f = 2 * wv + i;
        *(s16x8*)((char*)hdc + (((size_t)f * 16 + rank) * 64 + l) * 16) = (s16x8){0,0,0,0,0,0,0,0};
    }
    wave_arrive(cw, fastc);

    float hdq[2][2][4];                        // fp32 h-state in registers (decayed hd)
    #pragma unroll
    for (int mt = 0; mt < 2; ++mt)
        #pragma unroll
        for (int nt = 0; nt < 2; ++nt)
            #pragma unroll
            for (int q = 0; q < 4; ++q) hdq[mt][nt][q] = 0.f;
    float zq[2][2][4];

    for (int t = 0; t < T_LEN; ++t) {
        // ---- per-wave scalars for t (overlaps event poll) ----
        if (l < 32) {
            size_t idx = (size_t)(r0 + wv * 32 + l) * T_LEN + t;
            float xv = x[idx], xlv = xl[idx], iv = itv[idx], mv = msk[idx];
            float gx = __expf(-fmaxf(iv * wgx + bgx0, 0.f));
            xi_w[wv][l]  = mv * xv + (1.f - mv) * (gx * xlv + (1.f - gx) * xmv);
            mts_w[wv][l] = mv;
        }
        wave_wait(cw, (unsigned int)(16 * (2 * t + 1)), fastc);   // hd(t) ready (this wave-index)

        // ---- GEMM1: z,r for rows [32wv,32wv+32) x own 32 cols ----
        f32x4 accz[2][2], accr[2][2];
        #pragma unroll
        for (int mt = 0; mt < 2; ++mt)
            #pragma unroll
            for (int nt = 0; nt < 2; ++nt) { accz[mt][nt] = (f32x4){0,0,0,0}; accr[mt][nt] = (f32x4){0,0,0,0}; }
        #pragma unroll
        for (int kt = 0; kt < 16; ++kt) {
            s16x8 a0 = HD[((2 * wv    ) * 16 + kt) * 64 + l];
            s16x8 a1 = HD[((2 * wv + 1) * 16 + kt) * 64 + l];
            #pragma unroll
            for (int nt = 0; nt < 2; ++nt) {
                s16x8 bz_ = WF[(     nt * 16 + kt) * 64 + l];
                s16x8 br_ = WF[(32 + nt * 16 + kt) * 64 + l];
                accz[0][nt] = __builtin_amdgcn_mfma_f32_16x16x32_bf16(a0, bz_, accz[0][nt], 0, 0, 0);
                accz[1][nt] = __builtin_amdgcn_mfma_f32_16x16x32_bf16(a1, bz_, accz[1][nt], 0, 0, 0);
                accr[0][nt] = __builtin_amdgcn_mfma_f32_16x16x32_bf16(a0, br_, accr[0][nt], 0, 0, 0);
                accr[1][nt] = __builtin_amdgcn_mfma_f32_16x16x32_bf16(a1, br_, accr[1][nt], 0, 0, 0);
            }
        }
        // ---- z,r epilogue: z -> regs, r*hd -> stage (wave-own frags) ----
        #pragma unroll
        for (int mt = 0; mt < 2; ++mt) {
            #pragma unroll
            for (int nt = 0; nt < 2; ++nt) {
                int c = nt * 16 + colb;
                float4 ez = epi_s[c];
                float4 er = epi_s[32 + c];
                int grp = (c >> 3) & 3, jj = c & 7;
                #pragma unroll
                for (int q = 0; q < 4; ++q) {
                    int lr = mt * 16 + qg * 4 + q;            // local row in wave
                    float xiv = xi_w[wv][lr], mtv = mts_w[wv][lr];
                    zq[mt][nt][q] = sigmoid_f(accz[mt][nt][q] + ez.x + xiv * ez.y + mtv * ez.z);
                    float rr = sigmoid_f(accr[mt][nt][q] + er.x + xiv * er.y + mtv * er.z);
                    stage[(((2 * wv + mt) * 64) + (qg * 4 + q) + grp * 16) * 8 + jj] =
                        f2bf(rr * hdq[mt][nt][q]);
                }
            }
        }
        // ---- wave-private copy stage -> rhc ----
        #pragma unroll
        for (int i = 0; i < 2; ++i) {
            int f = 2 * wv + i;
            *(s16x8*)((char*)rhc + (((size_t)f * 16 + rank) * 64 + l) * 16) =
                *(const s16x8*)&stage[(f * 64 + l) * 8];
        }
        wave_arrive(cw, fastc);                                   // event 2t+2: rhd(t) published

        if (l < 32 && t + 1 < T_LEN)                              // its(t+1) overlaps poll
            itn_w[wv][l] = itv[(size_t)(r0 + wv * 32 + l) * T_LEN + t + 1];
        wave_wait(cw, (unsigned int)(16 * (2 * t + 2)), fastc);   // rhd(t) ready

        // ---- GEMM2: h~ ----
        f32x4 acc2[2][2];
        #pragma unroll
        for (int mt = 0; mt < 2; ++mt)
            #pragma unroll
            for (int nt = 0; nt < 2; ++nt) acc2[mt][nt] = (f32x4){0,0,0,0};
        #pragma unroll
        for (int kt = 0; kt < 16; ++kt) {
            s16x8 a0 = RH[((2 * wv    ) * 16 + kt) * 64 + l];
            s16x8 a1 = RH[((2 * wv + 1) * 16 + kt) * 64 + l];
            #pragma unroll
            for (int nt = 0; nt < 2; ++nt) {
                s16x8 bh_ = WF[(64 + nt * 16 + kt) * 64 + l];
                acc2[0][nt] = __builtin_amdgcn_mfma_f32_16x16x32_bf16(a0, bh_, acc2[0][nt], 0, 0, 0);
                acc2[1][nt] = __builtin_amdgcn_mfma_f32_16x16x32_bf16(a1, bh_, acc2[1][nt], 0, 0, 0);
            }
        }
        // ---- h~ epilogue + fused state update + fused gamma(t+1) decay ----
        const bool last = (t + 1 == T_LEN);
        #pragma unroll
        for (int mt = 0; mt < 2; ++mt) {
            #pragma unroll
            for (int nt = 0; nt < 2; ++nt) {
                int c = nt * 16 + colb;
                float4 eh = epi_s[64 + c];
                float2 gb = ghb_s[c];
                int grp = (c >> 3) & 3, jj = c & 7;
                #pragma unroll
                for (int q = 0; q < 4; ++q) {
                    int lr = mt * 16 + qg * 4 + q;
                    float ht = tanh_f(acc2[mt][nt][q] + eh.x + xi_w[wv][lr] * eh.y + mts_w[wv][lr] * eh.z);
                    float hd = hdq[mt][nt][q];
                    float hn = hd + zq[mt][nt][q] * (ht - hd);
                    float g  = last ? 1.f : __expf(-fmaxf(itn_w[wv][lr] * gb.x + gb.y, 0.f));
                    float hdn = hn * g;
                    hdq[mt][nt][q] = hdn;
                    if (!last)
                        stage[(((2 * wv + mt) * 64) + (qg * 4 + q) + grp * 16) * 8 + jj] = f2bf(hdn);
                }
            }
        }
        if (!last) {
            #pragma unroll
            for (int i = 0; i < 2; ++i) {
                int f = 2 * wv + i;
                *(s16x8*)((char*)hdc + (((size_t)f * 16 + rank) * 64 + l) * 16) =
                    *(const s16x8*)&stage[(f * 64 + l) * 8];
            }
        }
        wave_arrive(cw, fastc);                                   // event 2t+3: hd(t+1) published
    }

    // ---- output head: per-thread partials over own cols, 16-lane shfl reduce ----
    {
        float wo0 = Wo[rank * OWNC + colb];
        float wo1 = Wo[rank * OWNC + 16 + colb];
        #pragma unroll
        for (int mt = 0; mt < 2; ++mt) {
            #pragma unroll
            for (int q = 0; q < 4; ++q) {
                int row = wv * 32 + mt * 16 + qg * 4 + q;
                float p = hdq[mt][0][q] * wo0 + hdq[mt][1][q] * wo1;
                #pragma unroll
                for (int off = 1; off < 16; off <<= 1) p += __shfl_xor(p, off);
                if (colb == 0) osum[(size_t)(r0 + row) * RANKS + rank] = p;
            }
        }
    }
    bar_slow(base, 2 * RANKS);                 // slow-counter use #2 (fenced, any placement)
    if (rank == 0 && tid < CROWS) {
        float s = 0.f;
        #pragma unroll
        for (int rk = 0; rk < RANKS; ++rk) s += osum[(size_t)(r0 + tid) * RANKS + rk];
        out[r0 + tid] = sigmoid_f(s + bo[0]);
    }
}

extern "C" void kernel_launch(void* const* d_in, const int* in_sizes, int n_in,
                              void* d_out, int out_size, void* d_ws, size_t ws_size,
                              hipStream_t stream) {
    const float* x    = (const float*)d_in[0];
    const float* xl   = (const float*)d_in[1];
    const float* itv  = (const float*)d_in[2];
    const float* msk  = (const float*)d_in[3];
    const float* Wgx  = (const float*)d_in[4];
    const float* bgx  = (const float*)d_in[5];
    const float* Wgh  = (const float*)d_in[6];
    const float* bgh  = (const float*)d_in[7];
    const float* Wz   = (const float*)d_in[8];
    const float* bz   = (const float*)d_in[9];
    const float* Wr   = (const float*)d_in[10];
    const float* br   = (const float*)d_in[11];
    const float* Wh   = (const float*)d_in[12];
    const float* bh   = (const float*)d_in[13];
    const float* Wo   = (const float*)d_in[14];
    const float* bo   = (const float*)d_in[15];

    char* ws = (char*)d_ws;
    float*        xmean = (float*)ws;                               // 16384 B
    unsigned int* barc  = (unsigned int*)(ws + 16384);              // 16*1024 B = 16384 B
    float*        osum  = (float*)(ws + 32768);                     // 262144 B
    ushort*       hdx   = (ushort*)(ws + 32768 + 262144);           // 4 MB
    ushort*       rhx   = (ushort*)(ws + 32768 + 262144 + 4194304); // 4 MB

    k_init<<<16, 256, 0, stream>>>(barc);
    k_xmean<<<B_TOT, 64, 0, stream>>>(x, msk, xmean);
    k_grud<<<CLUSTERS * RANKS, NTHR, 0, stream>>>(
        x, xl, itv, msk, Wgx, bgx, Wgh, bgh,
        Wz, bz, Wr, br, Wh, bh, Wo, bo,
        xmean, hdx, rhx, osum, barc, (float*)d_out);
}